// Round 1
// baseline (346.235 us; speedup 1.0000x reference)
//
#include <hip/hip_runtime.h>
#include <cstdint>
#include <cstddef>

typedef unsigned int u32;
typedef unsigned short u16;
typedef __bf16 bf16x8 __attribute__((ext_vector_type(8)));
typedef float f32x4 __attribute__((ext_vector_type(4)));
typedef u32 u32x4 __attribute__((ext_vector_type(4)));
typedef u16 u16x8 __attribute__((ext_vector_type(8)));

#define B_ 4
#define N_ 2048
#define C_ 1024
#define H_ 16
#define D_ 64

#if __has_builtin(__builtin_amdgcn_exp2f)
#define EXP2F __builtin_amdgcn_exp2f
#else
#define EXP2F exp2f
#endif

__device__ __forceinline__ u16 bf16rn(float f) {
  u32 u = __builtin_bit_cast(u32, f);
  return (u16)((u + 0x7FFFu + ((u >> 16) & 1u)) >> 16);
}
__device__ __forceinline__ float bf2f(u16 h) {
  u32 u = ((u32)h) << 16;
  return __builtin_bit_cast(float, u);
}
__device__ __forceinline__ u32 cvtpk_bf16(float lo, float hi) {
  u32 r;
  asm("v_cvt_pk_bf16_f32 %0, %1, %2" : "=v"(r) : "v"(lo), "v"(hi));
  return r;
}
__device__ __forceinline__ void gload16(const u16* g, u16* l) {
  __builtin_amdgcn_global_load_lds(
      (const __attribute__((address_space(1))) u32*)g,
      (__attribute__((address_space(3))) u32*)l, 16, 0, 0);
}

// ---------------- pack f32 -> bf16 (8 elems/thread) ----------------
__global__ __launch_bounds__(256) void pack_bf16(const float* __restrict__ in,
                                                 u16* __restrict__ out, int n8) {
  int i = blockIdx.x * 256 + threadIdx.x;
  if (i >= n8) return;
  const float4* p4 = (const float4*)in + (size_t)i * 2;
  float4 a = p4[0], b = p4[1];
  u16x8 v;
  v[0] = bf16rn(a.x); v[1] = bf16rn(a.y); v[2] = bf16rn(a.z); v[3] = bf16rn(a.w);
  v[4] = bf16rn(b.x); v[5] = bf16rn(b.y); v[6] = bf16rn(b.z); v[7] = bf16rn(b.w);
  *((u16x8*)out + i) = v;
}

// ---------------- RMSNorm + RoPE, wave per row, in place ----------------
// q additionally pre-scaled by (1/sqrt(D)) * log2(e) so attn can use exp2.
__global__ __launch_bounds__(256)
void norm_rope(u16* __restrict__ q, u16* __restrict__ k,
               const float* __restrict__ qw, const float* __restrict__ kw,
               const float* __restrict__ cost, const float* __restrict__ sint) {
  const int lane = threadIdx.x & 63, wid = threadIdx.x >> 6;
  const int row = blockIdx.x * 4 + wid;              // 0 .. 2*B*H*N-1
  const int isk = row >= (B_ * H_ * N_);
  const int bhn = isk ? row - B_ * H_ * N_ : row;
  const int n = bhn & (N_ - 1);
  u16* base = (isk ? k : q) + (size_t)bhn * D_;
  float v = bf2f(base[lane]);
  float s = v * v;
#pragma unroll
  for (int off = 1; off < 64; off <<= 1) s += __shfl_xor(s, off);
  float w = (isk ? kw : qw)[lane];
  float r = rsqrtf(s * (1.0f / 64.0f) + 1e-6f);
  float vn = v * r * w;
  float part = __shfl_xor(vn, 32);
  float rot = (lane < 32) ? -part : part;
  float cv = cost[n * D_ + lane], sv = sint[n * D_ + lane];
  float res = vn * cv + rot * sv;
  if (!isk) res *= 0.125f * 1.44269504088896340736f;
  base[lane] = bf16rn(res);
}

// ---------------- m97-structure bf16 GEMM, C = A * Bt^T ----------------
// A: [M][K] bf16, Bt: [Nd][K] bf16. 128x128 tile, BK=32, 4 waves.
// EPI 0: qkv scatter epilogue (q,k -> [B,H,N,D] bf16; v -> [B,H,D,N] bf16)
// EPI 1: plain fp32 epilogue with bias.
template <int EPI>
__global__ __launch_bounds__(256)
void gemm_bt(const u16* __restrict__ A, const u16* __restrict__ Bt,
             int M, int Nd, int K, const float* __restrict__ bias,
             u16* __restrict__ qo, u16* __restrict__ ko, u16* __restrict__ vto,
             float* __restrict__ fo) {
  __shared__ u16 As[128 * 32];
  __shared__ u16 Bs[128 * 32];
  const int tid = threadIdx.x;
  const int lane = tid & 63;
  const int wid = tid >> 6;
  const int wr = wid >> 1, wc = wid & 1;
  const int l15 = lane & 15, g = lane >> 4;
  const int nm = M >> 7;
  const int bm = blockIdx.x % nm, bn = blockIdx.x / nm;
  const long m0 = (long)bm * 128, n0 = (long)bn * 128;
  const int r0 = tid >> 2, c0 = (tid & 3) * 8;  // 16B chunk: rows 0..63 (+64 for chunk1)
  const u16* Ag = A + m0 * K;
  const u16* Bg = Bt + n0 * K;
  f32x4 acc[4][4] = {};

  for (int kt = 0; kt < K; kt += 32) {
    __syncthreads();
    gload16(Ag + (long)r0 * K + kt + c0, (u16*)((char*)As + tid * 16));
    gload16(Ag + (long)(r0 + 64) * K + kt + c0, (u16*)((char*)As + tid * 16 + 4096));
    gload16(Bg + (long)r0 * K + kt + c0, (u16*)((char*)Bs + tid * 16));
    gload16(Bg + (long)(r0 + 64) * K + kt + c0, (u16*)((char*)Bs + tid * 16 + 4096));
    __syncthreads();
    bf16x8 af[4], bfr[4];
#pragma unroll
    for (int i = 0; i < 4; i++)
      af[i] = *(const bf16x8*)(As + (wr * 64 + i * 16 + l15) * 32 + g * 8);
#pragma unroll
    for (int i = 0; i < 4; i++)
      bfr[i] = *(const bf16x8*)(Bs + (wc * 64 + i * 16 + l15) * 32 + g * 8);
#pragma unroll
    for (int i = 0; i < 4; i++)
#pragma unroll
      for (int j = 0; j < 4; j++)
        acc[i][j] = __builtin_amdgcn_mfma_f32_16x16x32_bf16(af[i], bfr[j], acc[i][j], 0, 0, 0);
  }

  if (EPI == 0) {
#pragma unroll
    for (int nj = 0; nj < 4; nj++) {
      const int o = (int)n0 + wc * 64 + nj * 16 + l15;
      const float bv = bias[o];
      const int seg = o >> 10, c2 = o & 1023, h = c2 >> 6, d = c2 & 63;
#pragma unroll
      for (int mi = 0; mi < 4; mi++) {
        const int m = (int)m0 + wr * 64 + mi * 16 + g * 4;
        const int b = m >> 11, nt = m & 2047;
        if (seg == 2) {
          const long vbase = (((long)(b * 16 + h)) * 64 + d) * 2048 + nt;
          u16 pk[4];
#pragma unroll
          for (int j = 0; j < 4; j++) pk[j] = bf16rn(acc[mi][nj][j] + bv);
          uint2 val;
          val.x = (u32)pk[0] | ((u32)pk[1] << 16);
          val.y = (u32)pk[2] | ((u32)pk[3] << 16);
          *(uint2*)(vto + vbase) = val;
        } else {
          const long qkbase = (((long)(b * 16 + h)) * 2048 + nt) * 64 + d;
          u16* dst = (seg == 0 ? qo : ko) + qkbase;
#pragma unroll
          for (int j = 0; j < 4; j++) dst[(long)j * 64] = bf16rn(acc[mi][nj][j] + bv);
        }
      }
    }
  } else {
#pragma unroll
    for (int nj = 0; nj < 4; nj++) {
      const int o = (int)n0 + wc * 64 + nj * 16 + l15;
      const float bv = bias[o];
#pragma unroll
      for (int mi = 0; mi < 4; mi++) {
        const long m = m0 + wr * 64 + mi * 16 + g * 4;
#pragma unroll
        for (int j = 0; j < 4; j++) fo[(m + j) * (long)Nd + o] = acc[mi][nj][j] + bv;
      }
    }
  }
}

// ---------------- flash attention, 1 wave/block, 64 q rows/wave ----------------
// Swapped QK^T: S^T = mfma(K, Q), lane holds S^T[key=g*4+j (+16/frag)][q=l15].
// q pre-scaled by 0.125*log2e so p = exp2(s - m).
__global__ __launch_bounds__(64)
void attn_fwd(const u16* __restrict__ qb, const u16* __restrict__ kb,
              const u16* __restrict__ vt, u16* __restrict__ ob) {
  const int lane = threadIdx.x & 63;
  const int l15 = lane & 15, g = lane >> 4;
  const int bid = blockIdx.x;
  // XCD-aware swizzle: 2048 blocks, 8 XCDs, 8 bh per XCD (K/V set ~= 4MB L2)
  const int xcd = bid & 7, idx = bid >> 3;
  const int bh = xcd * 8 + (idx >> 5);
  const int q0 = (idx & 31) * 64;
  const u16* Q = qb + (size_t)bh * N_ * D_;
  const u16* Kp = kb + (size_t)bh * N_ * D_;
  const u16* Vt = vt + (size_t)bh * D_ * N_;

  bf16x8 qf[4][2];
#pragma unroll
  for (int t = 0; t < 4; t++) {
    qf[t][0] = *(const bf16x8*)(Q + (q0 + t * 16 + l15) * 64 + g * 8);
    qf[t][1] = *(const bf16x8*)(Q + (q0 + t * 16 + l15) * 64 + 32 + g * 8);
  }
  f32x4 oacc[4][4] = {};
  float m_run[4], l_run[4];
#pragma unroll
  for (int t = 0; t < 4; t++) { m_run[t] = -1e30f; l_run[t] = 0.0f; }

  const int srcA = l15 + (((g << 1) + 0) & 3) * 16;
  const int srcB = l15 + (((g << 1) + 1) & 3) * 16;
  const bool hi = (g >= 2);

  for (int k0 = 0; k0 < N_; k0 += 32) {
    const u16* Kr = Kp + (size_t)k0 * 64;
    const bf16x8 kf00 = *(const bf16x8*)(Kr + l15 * 64 + g * 8);
    const bf16x8 kf01 = *(const bf16x8*)(Kr + l15 * 64 + 32 + g * 8);
    const bf16x8 kf10 = *(const bf16x8*)(Kr + (16 + l15) * 64 + g * 8);
    const bf16x8 kf11 = *(const bf16x8*)(Kr + (16 + l15) * 64 + 32 + g * 8);
    bf16x8 vf[4];
#pragma unroll
    for (int dc = 0; dc < 4; dc++)
      vf[dc] = *(const bf16x8*)(Vt + (size_t)(dc * 16 + l15) * 2048 + k0 + g * 8);

#pragma unroll
    for (int t = 0; t < 4; t++) {
      f32x4 s0 = {}, s1 = {};
      s0 = __builtin_amdgcn_mfma_f32_16x16x32_bf16(kf00, qf[t][0], s0, 0, 0, 0);
      s0 = __builtin_amdgcn_mfma_f32_16x16x32_bf16(kf01, qf[t][1], s0, 0, 0, 0);
      s1 = __builtin_amdgcn_mfma_f32_16x16x32_bf16(kf10, qf[t][0], s1, 0, 0, 0);
      s1 = __builtin_amdgcn_mfma_f32_16x16x32_bf16(kf11, qf[t][1], s1, 0, 0, 0);

      float rm = fmaxf(fmaxf(fmaxf(s0[0], s0[1]), fmaxf(s0[2], s0[3])),
                       fmaxf(fmaxf(s1[0], s1[1]), fmaxf(s1[2], s1[3])));
      rm = fmaxf(rm, __shfl_xor(rm, 16));
      rm = fmaxf(rm, __shfl_xor(rm, 32));
      const float mnew = fmaxf(m_run[t], rm);
      const float corr = EXP2F(m_run[t] - mnew);
      const float p0 = EXP2F(s0[0] - mnew), p1 = EXP2F(s0[1] - mnew);
      const float p2 = EXP2F(s0[2] - mnew), p3 = EXP2F(s0[3] - mnew);
      const float p4 = EXP2F(s1[0] - mnew), p5 = EXP2F(s1[1] - mnew);
      const float p6 = EXP2F(s1[2] - mnew), p7 = EXP2F(s1[3] - mnew);
      float rs = ((p0 + p1) + (p2 + p3)) + ((p4 + p5) + (p6 + p7));
      rs += __shfl_xor(rs, 16);
      rs += __shfl_xor(rs, 32);
      l_run[t] = l_run[t] * corr + rs;
      m_run[t] = mnew;
#pragma unroll
      for (int dc = 0; dc < 4; dc++) {
        oacc[t][dc][0] *= corr; oacc[t][dc][1] *= corr;
        oacc[t][dc][2] *= corr; oacc[t][dc][3] *= corr;
      }
      // pack P to bf16 and lane-transpose into PV B-operand layout
      const u32 d0 = cvtpk_bf16(p0, p1), d1 = cvtpk_bf16(p2, p3);
      const u32 d2 = cvtpk_bf16(p4, p5), d3 = cvtpk_bf16(p6, p7);
      const u32 t0a = __shfl(d0, srcA), t0b = __shfl(d2, srcA);
      const u32 t1a = __shfl(d1, srcA), t1b = __shfl(d3, srcA);
      const u32 t2a = __shfl(d0, srcB), t2b = __shfl(d2, srcB);
      const u32 t3a = __shfl(d1, srcB), t3b = __shfl(d3, srcB);
      u32x4 pw;
      pw[0] = hi ? t0b : t0a;
      pw[1] = hi ? t1b : t1a;
      pw[2] = hi ? t2b : t2a;
      pw[3] = hi ? t3b : t3a;
      const bf16x8 pb = __builtin_bit_cast(bf16x8, pw);
#pragma unroll
      for (int dc = 0; dc < 4; dc++)
        oacc[t][dc] = __builtin_amdgcn_mfma_f32_16x16x32_bf16(vf[dc], pb, oacc[t][dc], 0, 0, 0);
    }
  }

  const int b = bh >> 4, h = bh & 15;
#pragma unroll
  for (int t = 0; t < 4; t++) {
    const float inv = 1.0f / l_run[t];
    const size_t mm = (size_t)b * 2048 + q0 + t * 16 + l15;
    u16* orow = ob + mm * 1024 + h * 64;
#pragma unroll
    for (int dc = 0; dc < 4; dc++) {
      const u16 e0 = bf16rn(oacc[t][dc][0] * inv);
      const u16 e1 = bf16rn(oacc[t][dc][1] * inv);
      const u16 e2 = bf16rn(oacc[t][dc][2] * inv);
      const u16 e3 = bf16rn(oacc[t][dc][3] * inv);
      uint2 val;
      val.x = (u32)e0 | ((u32)e1 << 16);
      val.y = (u32)e2 | ((u32)e3 << 16);
      *(uint2*)(orow + dc * 16 + g * 4) = val;
    }
  }
}

// ---------------- host launch ----------------
extern "C" void kernel_launch(void* const* d_in, const int* in_sizes, int n_in,
                              void* d_out, int out_size, void* d_ws, size_t ws_size,
                              hipStream_t stream) {
  (void)in_sizes; (void)n_in; (void)out_size; (void)ws_size;
  const float* x = (const float*)d_in[0];
  const float* qkvw = (const float*)d_in[1];
  const float* qkvb = (const float*)d_in[2];
  const float* projw = (const float*)d_in[3];
  const float* projb = (const float*)d_in[4];
  const float* qnw = (const float*)d_in[5];
  const float* knw = (const float*)d_in[6];
  const float* cost = (const float*)d_in[7];
  const float* sint = (const float*)d_in[8];
  float* out = (float*)d_out;

  char* ws = (char*)d_ws;
  u16* xb = (u16*)ws;        ws += (size_t)8192 * 1024 * 2;   // A for qkv gemm
  u16* wb = (u16*)ws;        ws += (size_t)3072 * 1024 * 2;   // qkv_w bf16
  u16* pwb = (u16*)ws;       ws += (size_t)1024 * 1024 * 2;   // proj_w bf16
  u16* qraw = (u16*)ws;      ws += (size_t)8192 * 1024 * 2;   // q [B,H,N,D] (normed in place)
  u16* kraw = (u16*)ws;      ws += (size_t)8192 * 1024 * 2;   // k [B,H,N,D]
  u16* vt = (u16*)ws;        ws += (size_t)8192 * 1024 * 2;   // v^T [B,H,D,N]
  u16* ob = (u16*)ws;        ws += (size_t)8192 * 1024 * 2;   // attn out [B*N, C]
  // total 88 MB

  pack_bf16<<<dim3(8192 * 1024 / 8 / 256), dim3(256), 0, stream>>>(x, xb, 8192 * 1024 / 8);
  pack_bf16<<<dim3(3072 * 1024 / 8 / 256), dim3(256), 0, stream>>>(qkvw, wb, 3072 * 1024 / 8);
  pack_bf16<<<dim3(1024 * 1024 / 8 / 256), dim3(256), 0, stream>>>(projw, pwb, 1024 * 1024 / 8);

  gemm_bt<0><<<dim3(64 * 24), dim3(256), 0, stream>>>(xb, wb, 8192, 3072, 1024, qkvb,
                                                      qraw, kraw, vt, nullptr);
  norm_rope<<<dim3(2 * B_ * H_ * N_ / 4), dim3(256), 0, stream>>>(qraw, kraw, qnw, knw, cost, sint);
  attn_fwd<<<dim3(2048), dim3(64), 0, stream>>>(qraw, kraw, vt, ob);
  gemm_bt<1><<<dim3(64 * 8), dim3(256), 0, stream>>>(ob, pwb, 8192, 1024, 1024, projb,
                                                     nullptr, nullptr, nullptr, out);
}

// Round 5
// 272.846 us; speedup vs baseline: 1.2690x; 1.2690x over previous
//
#include <hip/hip_runtime.h>
#include <cstdint>
#include <cstddef>

typedef unsigned int u32;
typedef unsigned short u16;
typedef __bf16 bf16x8 __attribute__((ext_vector_type(8)));
typedef float f32x4 __attribute__((ext_vector_type(4)));
typedef u32 u32x4 __attribute__((ext_vector_type(4)));
typedef u16 u16x8 __attribute__((ext_vector_type(8)));

#define B_ 4
#define N_ 2048
#define C_ 1024
#define H_ 16
#define D_ 64

#if __has_builtin(__builtin_amdgcn_exp2f)
#define EXP2F __builtin_amdgcn_exp2f
#else
#define EXP2F exp2f
#endif

__device__ __forceinline__ u16 bf16rn(float f) {
  u32 u = __builtin_bit_cast(u32, f);
  return (u16)((u + 0x7FFFu + ((u >> 16) & 1u)) >> 16);
}
__device__ __forceinline__ float bf2f(u16 h) {
  u32 u = ((u32)h) << 16;
  return __builtin_bit_cast(float, u);
}
__device__ __forceinline__ u32 cvtpk_bf16(float lo, float hi) {
  u32 r;
  asm("v_cvt_pk_bf16_f32 %0, %1, %2" : "=v"(r) : "v"(lo), "v"(hi));
  return r;
}

__device__ __forceinline__ void gload16(const u16* g, u16* l) {
  __builtin_amdgcn_global_load_lds(
      (const __attribute__((address_space(1))) u32*)g,
      (__attribute__((address_space(3))) u32*)l, 16, 0, 0);
}

// ---------------- pack f32 -> bf16 (8 elems/thread) ----------------
__global__ __launch_bounds__(256) void pack_bf16(const float* __restrict__ in,
                                                 u16* __restrict__ out, int n8) {
  int i = blockIdx.x * 256 + threadIdx.x;
  if (i >= n8) return;
  const float4* p4 = (const float4*)in + (size_t)i * 2;
  float4 a = p4[0], b = p4[1];
  u16x8 v;
  v[0] = bf16rn(a.x); v[1] = bf16rn(a.y); v[2] = bf16rn(a.z); v[3] = bf16rn(a.w);
  v[4] = bf16rn(b.x); v[5] = bf16rn(b.y); v[6] = bf16rn(b.z); v[7] = bf16rn(b.w);
  *((u16x8*)out + i) = v;
}

// ---------------- RMSNorm + RoPE, wave per row, in place ----------------
// q additionally pre-scaled by (1/sqrt(D)) * log2(e) so attn can use exp2.
__global__ __launch_bounds__(256)
void norm_rope(u16* __restrict__ q, u16* __restrict__ k,
               const float* __restrict__ qw, const float* __restrict__ kw,
               const float* __restrict__ cost, const float* __restrict__ sint) {
  const int lane = threadIdx.x & 63, wid = threadIdx.x >> 6;
  const int row = blockIdx.x * 4 + wid;              // 0 .. 2*B*H*N-1
  const int isk = row >= (B_ * H_ * N_);
  const int bhn = isk ? row - B_ * H_ * N_ : row;
  const int n = bhn & (N_ - 1);
  u16* base = (isk ? k : q) + (size_t)bhn * D_;
  float v = bf2f(base[lane]);
  float s = v * v;
#pragma unroll
  for (int off = 1; off < 64; off <<= 1) s += __shfl_xor(s, off);
  float w = (isk ? kw : qw)[lane];
  float r = rsqrtf(s * (1.0f / 64.0f) + 1e-6f);
  float vn = v * r * w;
  float part = __shfl_xor(vn, 32);
  float rot = (lane < 32) ? -part : part;
  float cv = cost[n * D_ + lane], sv = sint[n * D_ + lane];
  float res = vn * cv + rot * sv;
  if (!isk) res *= 0.125f * 1.44269504088896340736f;
  base[lane] = bf16rn(res);
}

// ---------------- m97-structure bf16 GEMM, C = A * Bt^T ----------------
template <int EPI>
__global__ __launch_bounds__(256)
void gemm_bt(const u16* __restrict__ A, const u16* __restrict__ Bt,
             int M, int Nd, int K, const float* __restrict__ bias,
             u16* __restrict__ qo, u16* __restrict__ ko, u16* __restrict__ vto,
             float* __restrict__ fo) {
  __shared__ u16 As[128 * 32];
  __shared__ u16 Bs[128 * 32];
  const int tid = threadIdx.x;
  const int lane = tid & 63;
  const int wid = tid >> 6;
  const int wr = wid >> 1, wc = wid & 1;
  const int l15 = lane & 15, g = lane >> 4;
  const int nm = M >> 7;
  const int bm = blockIdx.x % nm, bn = blockIdx.x / nm;
  const long m0 = (long)bm * 128, n0 = (long)bn * 128;
  const int r0 = tid >> 2, c0 = (tid & 3) * 8;
  const u16* Ag = A + m0 * K;
  const u16* Bg = Bt + n0 * K;
  f32x4 acc[4][4] = {};

  for (int kt = 0; kt < K; kt += 32) {
    __syncthreads();
    gload16(Ag + (long)r0 * K + kt + c0, (u16*)((char*)As + tid * 16));
    gload16(Ag + (long)(r0 + 64) * K + kt + c0, (u16*)((char*)As + tid * 16 + 4096));
    gload16(Bg + (long)r0 * K + kt + c0, (u16*)((char*)Bs + tid * 16));
    gload16(Bg + (long)(r0 + 64) * K + kt + c0, (u16*)((char*)Bs + tid * 16 + 4096));
    __syncthreads();
    bf16x8 af[4], bfr[4];
#pragma unroll
    for (int i = 0; i < 4; i++)
      af[i] = *(const bf16x8*)(As + (wr * 64 + i * 16 + l15) * 32 + g * 8);
#pragma unroll
    for (int i = 0; i < 4; i++)
      bfr[i] = *(const bf16x8*)(Bs + (wc * 64 + i * 16 + l15) * 32 + g * 8);
#pragma unroll
    for (int i = 0; i < 4; i++)
#pragma unroll
      for (int j = 0; j < 4; j++)
        acc[i][j] = __builtin_amdgcn_mfma_f32_16x16x32_bf16(af[i], bfr[j], acc[i][j], 0, 0, 0);
  }

  if (EPI == 0) {
#pragma unroll
    for (int nj = 0; nj < 4; nj++) {
      const int o = (int)n0 + wc * 64 + nj * 16 + l15;
      const float bv = bias[o];
      const int seg = o >> 10, c2 = o & 1023, h = c2 >> 6, d = c2 & 63;
#pragma unroll
      for (int mi = 0; mi < 4; mi++) {
        const int m = (int)m0 + wr * 64 + mi * 16 + g * 4;
        const int b = m >> 11, nt = m & 2047;
        if (seg == 2) {
          const long vbase = (((long)(b * 16 + h)) * 64 + d) * 2048 + nt;
          u16 pk[4];
#pragma unroll
          for (int j = 0; j < 4; j++) pk[j] = bf16rn(acc[mi][nj][j] + bv);
          uint2 val;
          val.x = (u32)pk[0] | ((u32)pk[1] << 16);
          val.y = (u32)pk[2] | ((u32)pk[3] << 16);
          *(uint2*)(vto + vbase) = val;
        } else {
          const long qkbase = (((long)(b * 16 + h)) * 2048 + nt) * 64 + d;
          u16* dst = (seg == 0 ? qo : ko) + qkbase;
#pragma unroll
          for (int j = 0; j < 4; j++) dst[(long)j * 64] = bf16rn(acc[mi][nj][j] + bv);
        }
      }
    }
  } else {
#pragma unroll
    for (int nj = 0; nj < 4; nj++) {
      const int o = (int)n0 + wc * 64 + nj * 16 + l15;
      const float bv = bias[o];
#pragma unroll
      for (int mi = 0; mi < 4; mi++) {
        const long m = m0 + wr * 64 + mi * 16 + g * 4;
#pragma unroll
        for (int j = 0; j < 4; j++) fo[(m + j) * (long)Nd + o] = acc[mi][nj][j] + bv;
      }
    }
  }
}

// ---------------- flash attention, 16x16 swapped + sigma-permuted K ----------------
// Round-1-VERIFIED premises only:
//   A-operand row slot = l15 (feeding K row r into slot l15 makes D row r = key r)
//   B-operand k-map    = (lane>>4)*8 + j   (confirmed by round-1 working shuffles)
//   C/D layout         = col l15, row g*4+j (confirmed end-to-end in round 1)
// sigma: frag0 A-slot r holds K row k0 + (r>>2)*8 + (r&3); frag1 same +4.
// => lane g's s0[j] = S[key g*8+j][q], s1[j] = S[key g*8+4+j][q]  (j=0..3)
// => P is ALREADY in PV B-operand order: zero cross-lane ops for the transpose.
// 4 waves/block (64 q-rows each) for occupancy; exact rescale every tile.
__global__ __launch_bounds__(256, 2)
void attn_fwd(const u16* __restrict__ qb, const u16* __restrict__ kb,
              const u16* __restrict__ vt, u16* __restrict__ ob) {
  const int tid = threadIdx.x;
  const int lane = tid & 63;
  const int l15 = lane & 15, g = lane >> 4;
  const int wid = tid >> 6;
  const int bid = blockIdx.x;
  // 512 blocks over 8 XCDs; 8 bh per XCD -> K/V working set ~4MB = one L2
  const int xcd = bid & 7, idx = bid >> 3;
  const int bh = xcd * 8 + (idx >> 3);
  const int q0 = (idx & 7) * 256 + wid * 64;
  const u16* Q = qb + (size_t)bh * (N_ * D_);
  const u16* Kp = kb + (size_t)bh * (N_ * D_);
  const u16* Vt = vt + (size_t)bh * (D_ * N_);

  bf16x8 qf[4][2];
#pragma unroll
  for (int t = 0; t < 4; t++) {
    qf[t][0] = *(const bf16x8*)(Q + (size_t)(q0 + t * 16 + l15) * 64 + g * 8);
    qf[t][1] = *(const bf16x8*)(Q + (size_t)(q0 + t * 16 + l15) * 64 + 32 + g * 8);
  }
  f32x4 oacc[4][4] = {};
  float m_run[4], l_run[4];
#pragma unroll
  for (int t = 0; t < 4; t++) { m_run[t] = -1e30f; l_run[t] = 0.0f; }

  // sigma-permuted K row offsets (elements): frag0 row = (l15>>2)*8 + (l15&3)
  const int sig0 = ((l15 >> 2) * 8 + (l15 & 3)) * 64 + g * 8;
  const int sig1 = sig0 + 4 * 64;

  for (int k0 = 0; k0 < N_; k0 += 32) {
    const u16* Kr = Kp + (size_t)k0 * 64;
    const bf16x8 kf00 = *(const bf16x8*)(Kr + sig0);
    const bf16x8 kf01 = *(const bf16x8*)(Kr + sig0 + 32);
    const bf16x8 kf10 = *(const bf16x8*)(Kr + sig1);
    const bf16x8 kf11 = *(const bf16x8*)(Kr + sig1 + 32);
    bf16x8 vf[4];
#pragma unroll
    for (int dc = 0; dc < 4; dc++)
      vf[dc] = *(const bf16x8*)(Vt + (size_t)(dc * 16 + l15) * 2048 + k0 + g * 8);

#pragma unroll
    for (int t = 0; t < 4; t++) {
      f32x4 s0 = {}, s1 = {};
      s0 = __builtin_amdgcn_mfma_f32_16x16x32_bf16(kf00, qf[t][0], s0, 0, 0, 0);
      s0 = __builtin_amdgcn_mfma_f32_16x16x32_bf16(kf01, qf[t][1], s0, 0, 0, 0);
      s1 = __builtin_amdgcn_mfma_f32_16x16x32_bf16(kf10, qf[t][0], s1, 0, 0, 0);
      s1 = __builtin_amdgcn_mfma_f32_16x16x32_bf16(kf11, qf[t][1], s1, 0, 0, 0);

      float rm = fmaxf(fmaxf(fmaxf(s0[0], s0[1]), fmaxf(s0[2], s0[3])),
                       fmaxf(fmaxf(s1[0], s1[1]), fmaxf(s1[2], s1[3])));
      rm = fmaxf(rm, __shfl_xor(rm, 16));
      rm = fmaxf(rm, __shfl_xor(rm, 32));
      const float mnew = fmaxf(m_run[t], rm);
      const float corr = EXP2F(m_run[t] - mnew);
      const float p0 = EXP2F(s0[0] - mnew), p1 = EXP2F(s0[1] - mnew);
      const float p2 = EXP2F(s0[2] - mnew), p3 = EXP2F(s0[3] - mnew);
      const float p4 = EXP2F(s1[0] - mnew), p5 = EXP2F(s1[1] - mnew);
      const float p6 = EXP2F(s1[2] - mnew), p7 = EXP2F(s1[3] - mnew);
      float rs = ((p0 + p1) + (p2 + p3)) + ((p4 + p5) + (p6 + p7));
      rs += __shfl_xor(rs, 16);
      rs += __shfl_xor(rs, 32);
      l_run[t] = l_run[t] * corr + rs;
      m_run[t] = mnew;
#pragma unroll
      for (int dc = 0; dc < 4; dc++) {
        oacc[t][dc][0] *= corr; oacc[t][dc][1] *= corr;
        oacc[t][dc][2] *= corr; oacc[t][dc][3] *= corr;
      }
      // P already in B-operand order: keys g*8+0..7 = {p0..p3 (s0), p4..p7 (s1)}
      u32x4 pw;
      pw[0] = cvtpk_bf16(p0, p1);
      pw[1] = cvtpk_bf16(p2, p3);
      pw[2] = cvtpk_bf16(p4, p5);
      pw[3] = cvtpk_bf16(p6, p7);
      const bf16x8 pb = __builtin_bit_cast(bf16x8, pw);
#pragma unroll
      for (int dc = 0; dc < 4; dc++)
        oacc[t][dc] = __builtin_amdgcn_mfma_f32_16x16x32_bf16(vf[dc], pb, oacc[t][dc], 0, 0, 0);
    }
  }

  const int b = bh >> 4, h = bh & 15;
#pragma unroll
  for (int t = 0; t < 4; t++) {
    const float inv = 1.0f / l_run[t];
    const size_t mm = (size_t)b * 2048 + q0 + t * 16 + l15;
    u16* orow = ob + mm * 1024 + h * 64;
#pragma unroll
    for (int dc = 0; dc < 4; dc++) {
      uint2 val;
      val.x = cvtpk_bf16(oacc[t][dc][0] * inv, oacc[t][dc][1] * inv);
      val.y = cvtpk_bf16(oacc[t][dc][2] * inv, oacc[t][dc][3] * inv);
      *(uint2*)(orow + dc * 16 + g * 4) = val;
    }
  }
}

// ---------------- host launch ----------------
extern "C" void kernel_launch(void* const* d_in, const int* in_sizes, int n_in,
                              void* d_out, int out_size, void* d_ws, size_t ws_size,
                              hipStream_t stream) {
  (void)in_sizes; (void)n_in; (void)out_size; (void)ws_size;
  const float* x = (const float*)d_in[0];
  const float* qkvw = (const float*)d_in[1];
  const float* qkvb = (const float*)d_in[2];
  const float* projw = (const float*)d_in[3];
  const float* projb = (const float*)d_in[4];
  const float* qnw = (const float*)d_in[5];
  const float* knw = (const float*)d_in[6];
  const float* cost = (const float*)d_in[7];
  const float* sint = (const float*)d_in[8];
  float* out = (float*)d_out;

  char* ws = (char*)d_ws;
  u16* xb = (u16*)ws;        ws += (size_t)8192 * 1024 * 2;
  u16* wb = (u16*)ws;        ws += (size_t)3072 * 1024 * 2;
  u16* pwb = (u16*)ws;       ws += (size_t)1024 * 1024 * 2;
  u16* qraw = (u16*)ws;      ws += (size_t)8192 * 1024 * 2;
  u16* kraw = (u16*)ws;      ws += (size_t)8192 * 1024 * 2;
  u16* vt = (u16*)ws;        ws += (size_t)8192 * 1024 * 2;
  u16* ob = (u16*)ws;        ws += (size_t)8192 * 1024 * 2;

  pack_bf16<<<dim3(8192 * 1024 / 8 / 256), dim3(256), 0, stream>>>(x, xb, 8192 * 1024 / 8);
  pack_bf16<<<dim3(3072 * 1024 / 8 / 256), dim3(256), 0, stream>>>(qkvw, wb, 3072 * 1024 / 8);
  pack_bf16<<<dim3(1024 * 1024 / 8 / 256), dim3(256), 0, stream>>>(projw, pwb, 1024 * 1024 / 8);

  gemm_bt<0><<<dim3(64 * 24), dim3(256), 0, stream>>>(xb, wb, 8192, 3072, 1024, qkvb,
                                                      qraw, kraw, vt, nullptr);
  norm_rope<<<dim3(2 * B_ * H_ * N_ / 4), dim3(256), 0, stream>>>(qraw, kraw, qnw, knw, cost, sint);
  attn_fwd<<<dim3(512), dim3(256), 0, stream>>>(qraw, kraw, vt, ob);
  gemm_bt<1><<<dim3(64 * 8), dim3(256), 0, stream>>>(ob, pwb, 8192, 1024, 1024, projb,
                                                     nullptr, nullptr, nullptr, out);
}